// Round 1
// 528.300 us; speedup vs baseline: 1.0951x; 1.0951x over previous
//
#include <hip/hip_runtime.h>
#include <hip/hip_bf16.h>

#define BATCH   8192
#define IN_SZ   1024
#define HSZ     2048
#define GG      1024
#define KTOT    2048

typedef __hip_bfloat16 bf16;
typedef __attribute__((ext_vector_type(8))) short  short8;
typedef __attribute__((ext_vector_type(4))) short  short4e;
typedef __attribute__((ext_vector_type(4))) float  floatx4;

typedef __attribute__((address_space(1))) const void gvoid_t;
typedef __attribute__((address_space(3))) void       lvoid_t;

__device__ __forceinline__ void async_ld16(void* lds, const void* g) {
  __builtin_amdgcn_global_load_lds((gvoid_t*)g, (lvoid_t*)lds, 16, 0, 0);
}

// ---------------- fused prep: x->bf16, h2->bf16 float, 4 weight transposes --
__global__ void prep_all(const float* __restrict__ x, bf16* __restrict__ xb,
                         const int* __restrict__ hidden, bf16* __restrict__ hf,
                         float* accp,
                         const float* __restrict__ W_zr1, const float* __restrict__ W_g1,
                         const float* __restrict__ W_zr2, const float* __restrict__ W_g2,
                         bf16* __restrict__ wt_zr1, bf16* __restrict__ wt_g1,
                         bf16* __restrict__ wt_zr2, bf16* __restrict__ wt_g2) {
  int b = blockIdx.x;
  int t = threadIdx.x;
  if (b < 3072) {
    const float* W; bf16* Wt; int N; int tb = b;
    if (tb < 1024)      { W = W_zr1; Wt = wt_zr1; N = 2048; }
    else if (tb < 1536) { W = W_g1;  Wt = wt_g1;  N = 1024; tb -= 1024; }
    else if (tb < 2560) { W = W_zr2; Wt = wt_zr2; N = 2048; tb -= 1536; }
    else                { W = W_g2;  Wt = wt_g2;  N = 1024; tb -= 2560; }
    int ntn = N >> 6;
    int k0 = (tb / ntn) * 64, n0 = (tb % ntn) * 64;
    __shared__ float tile[64][65];
    int kk = t >> 4, nn = (t & 15) * 4;
#pragma unroll
    for (int s = 0; s < 4; ++s) {
      int row = kk + s * 16;
      float4 v = *(const float4*)&W[(size_t)(k0 + row) * N + n0 + nn];
      tile[row][nn + 0] = v.x; tile[row][nn + 1] = v.y;
      tile[row][nn + 2] = v.z; tile[row][nn + 3] = v.w;
    }
    __syncthreads();
    int k8 = (t & 7) * 8;
#pragma unroll
    for (int s = 0; s < 2; ++s) {
      int nl = (t >> 3) + s * 32;
      bf16 vals[8];
#pragma unroll
      for (int u = 0; u < 8; ++u) vals[u] = __float2bfloat16(tile[k8 + u][nl]);
      *(short8*)&Wt[(size_t)(n0 + nl) * KTOT + k0 + k8] = *(short8*)vals;
    }
  } else {
    int idx = (b - 3072) * 256 + t;
    int i = idx * 4;
    float4 xv = *(const float4*)(x + i);
    xb[i + 0] = __float2bfloat16(xv.x);
    xb[i + 1] = __float2bfloat16(xv.y);
    xb[i + 2] = __float2bfloat16(xv.z);
    xb[i + 3] = __float2bfloat16(xv.w);
    int m = i >> 10, j = i & 1023;
    int4 hv = *(const int4*)(hidden + m * HSZ + GG + j);
    const float sc = 1.0f / 8388608.0f;   // 2^-23
    hf[i + 0] = __float2bfloat16((float)hv.x * sc);
    hf[i + 1] = __float2bfloat16((float)hv.y * sc);
    hf[i + 2] = __float2bfloat16((float)hv.z * sc);
    hf[i + 3] = __float2bfloat16((float)hv.w * sc);
    if (idx == 0) *accp = 0.0f;
  }
}

// =============================================================================
// 8-phase pipelined mainloop (guide §5 template), BM=256, BK=64, 512 threads.
// 8 waves, 2(M)x4(N); per-wave tile 128 x (BN/4). LDS chunk XOR-swizzle as in
// the previous verified kernel: physical 16B chunk p of row r holds global
// k-chunk p ^ (r&7); staging pre-swizzles the GLOBAL source column, LDS dest
// stays linear (global_load_lds requirement), ds_read applies the same XOR.
// Double-buffered (tile even->buf0, odd->buf1). 2 K-tiles per iteration,
// 8 phases; each phase: {ds_read subtile | issue 1 half-tile prefetch |
// s_barrier | lgkmcnt(0) | setprio(1) MFMA cluster setprio(0) |
// [counted vmcnt at ph4/ph8 only] | s_barrier}.  vmcnt is NEVER 0 in-loop.
// =============================================================================

#define BAR() asm volatile("s_barrier" ::: "memory")

#define DS_A(buf, qm) do {                                                   \
  _Pragma("unroll") for (int ii = 0; ii < 4; ++ii) {                         \
    const bf16* _ap = As + (buf)*16384 + (wm*128 + (qm)*64 + ii*16 + r16)*64;\
    af[ii][0] = *(const short8*)(const void*)(_ap + pcq0);                   \
    af[ii][1] = *(const short8*)(const void*)(_ap + pcq1);                   \
  } } while (0)

#define DS_B(buf, qn) do {                                                   \
  _Pragma("unroll") for (int jj = 0; jj < NJQ; ++jj) {                       \
    const int _brow = (BN == 256) ? (wn*64 + (qn)*32 + jj*16 + r16)          \
                                  : (wn*32 + (qn)*16 + r16);                 \
    const bf16* _bp = Bs + (buf)*BSTR + _brow*64;                            \
    bfr[jj][0] = *(const short8*)(const void*)(_bp + pcq0);                  \
    bfr[jj][1] = *(const short8*)(const void*)(_bp + pcq1);                  \
  } } while (0)

#define MFMA_Q(qm, qn) do {                                                  \
  _Pragma("unroll") for (int ii = 0; ii < 4; ++ii)                           \
  _Pragma("unroll") for (int jj = 0; jj < NJQ; ++jj) {                       \
    floatx4& _c = acc[(qm)*4 + ii][(qn)*NJQ + jj];                           \
    _c = __builtin_amdgcn_mfma_f32_16x16x32_bf16(af[ii][0], bfr[jj][0], _c, 0, 0, 0); \
    _c = __builtin_amdgcn_mfma_f32_16x16x32_bf16(af[ii][1], bfr[jj][1], _c, 0, 0, 0); \
  } } while (0)

// A group (qm,h): rows h*128 + qm*64 + [0,64).  B group (qn,h): rows with
// "qn bit" set accordingly.  Each async call stages 64 rows (512 thr x 16B).
#define STAGE_A(buf, qm, tk) do {                                            \
  const int _t = (tk);                                                       \
  const bf16* _p = (_t < 16 ? A0 : A1);                                      \
  const int _k = ((_t & 15) << 6) + gch8;                                    \
  async_ld16(As + (buf)*16384 + (qm)*4096 + w*512 + lnoff,        _p + a_sro[qm][0] + _k); \
  async_ld16(As + (buf)*16384 + 8192 + (qm)*4096 + w*512 + lnoff, _p + a_sro[qm][1] + _k); \
} while (0)

#define STAGE_B(buf, qn, tk) do {                                            \
  const int _k = ((tk) << 6) + gch8;                                         \
  if constexpr (BN == 256) {                                                 \
    async_ld16(Bs + (buf)*BSTR + ((w>>2)*64 + (qn)*32 + (w&3)*8)*64 + lnoff,       Bt + b_sro[qn][0] + _k); \
    async_ld16(Bs + (buf)*BSTR + (128 + (w>>2)*64 + (qn)*32 + (w&3)*8)*64 + lnoff, Bt + b_sro[qn][1] + _k); \
  } else {                                                                   \
    async_ld16(Bs + (buf)*BSTR + ((w>>1)*32 + (qn)*16 + (w&1)*8)*64 + lnoff,       Bt + b_sro[qn][0] + _k); \
  }                                                                          \
} while (0)

#define PHASE(buf, qm, qn, NEWA, STAGE_STMT, DOVM) do {                      \
  if (NEWA) DS_A(buf, qm);                                                   \
  DS_B(buf, qn);                                                             \
  STAGE_STMT;                                                                \
  BAR();                                                                     \
  asm volatile("s_waitcnt lgkmcnt(0)" ::: "memory");                         \
  __builtin_amdgcn_sched_barrier(0);                                         \
  __builtin_amdgcn_s_setprio(1);                                             \
  MFMA_Q(qm, qn);                                                            \
  __builtin_amdgcn_s_setprio(0);                                             \
  if (DOVM) { if constexpr (BN == 256) asm volatile("s_waitcnt vmcnt(4)" ::: "memory"); \
              else                     asm volatile("s_waitcnt vmcnt(3)" ::: "memory"); } \
  BAR();                                                                     \
} while (0)

template<int BN>
__device__ __forceinline__ void mainloop8(const bf16* __restrict__ A0,
                                          const bf16* __restrict__ A1,
                                          const bf16* __restrict__ Bt,
                                          bf16* As, bf16* Bs,
                                          int m0, int n0,
                                          floatx4 (&acc)[8][BN / 64]) {
  constexpr int NJQ  = BN / 128;     // frag-cols per phase: 2 (zr) / 1 (g)
  constexpr int BSTR = BN * 64;      // B buffer stride (elements)
  const int t    = threadIdx.x;
  const int lane = t & 63;
  const int w    = t >> 6;
  const int l3   = lane >> 3;
  const int gch8 = (((lane & 7) ^ l3) << 3);   // pre-swizzled global k-chunk
  const int lnoff = lane << 3;
  const int wm = w & 1, wn = w >> 1;
  const int q = lane >> 4, r16 = lane & 15;
  const int pcq0 = ((q)     ^ (r16 & 7)) << 3;
  const int pcq1 = ((4 + q) ^ (r16 & 7)) << 3;

  int a_sro[2][2], b_sro[2][2];
#pragma unroll
  for (int qm = 0; qm < 2; ++qm)
#pragma unroll
    for (int h = 0; h < 2; ++h)
      a_sro[qm][h] = (m0 + h*128 + qm*64 + w*8 + l3) * 1024;
#pragma unroll
  for (int qn = 0; qn < 2; ++qn) {
    if constexpr (BN == 256) {
#pragma unroll
      for (int h = 0; h < 2; ++h)
        b_sro[qn][h] = (n0 + h*128 + (w>>2)*64 + qn*32 + (w&3)*8 + l3) * KTOT;
    } else {
      b_sro[qn][0] = (n0 + (w>>1)*32 + qn*16 + (w&1)*8 + l3) * KTOT;
      b_sro[qn][1] = 0;
    }
  }

  // prologue: tile0 -> buf0 (all 4 groups), tile1 -> buf1 (A-qm0, B-qn0)
  STAGE_A(0, 0, 0); STAGE_B(0, 0, 0);
  STAGE_A(0, 1, 0); STAGE_B(0, 1, 0);
  STAGE_A(1, 0, 1); STAGE_B(1, 0, 1);
  if constexpr (BN == 256) asm volatile("s_waitcnt vmcnt(4)" ::: "memory");
  else                     asm volatile("s_waitcnt vmcnt(3)" ::: "memory");
  BAR();

#pragma unroll 1
  for (int it = 0; it < KTOT / 128; ++it) {
    const int tO = 2*it + 1;                                   // odd tile (buf1)
    const int t2 = (2*it + 2 < KTOT/64) ? (2*it + 2) : (KTOT/64 - 1);
    const int t3 = (2*it + 3 < KTOT/64) ? (2*it + 3) : (KTOT/64 - 1);
    short8 af[4][2];
    short8 bfr[NJQ][2];
    // phases 1-4: compute tile 2i in buf0; phases 5-8: tile 2i+1 in buf1.
    // staging fills each region right after its last consumer phase.
    PHASE(0, 0, 0, 1, STAGE_A(1, 1, tO), 0);   // ph1
    PHASE(0, 0, 1, 0, STAGE_B(1, 1, tO), 0);   // ph2
    PHASE(0, 1, 0, 1, STAGE_A(0, 0, t2), 0);   // ph3
    PHASE(0, 1, 1, 0, STAGE_B(0, 0, t2), 1);   // ph4  + vmcnt
    PHASE(1, 0, 0, 1, STAGE_A(0, 1, t2), 0);   // ph5
    PHASE(1, 0, 1, 0, STAGE_B(0, 1, t2), 0);   // ph6
    PHASE(1, 1, 0, 1, STAGE_A(1, 0, t3), 0);   // ph7
    PHASE(1, 1, 1, 0, STAGE_B(1, 0, t3), 1);   // ph8  + vmcnt
  }
  asm volatile("s_waitcnt vmcnt(0)" ::: "memory");  // drain before LDS reuse
  __syncthreads();
}

// ---------------- zr stage (256x256): sigmoid; z -> zbuf(bf16)+bits; r -> r*h
// Epilogue: accumulator -> LDS f32 (XOR-swizzled) -> coalesced 8B stores.
__global__ void __launch_bounds__(512, 2)
gemm_zr8(const bf16* __restrict__ xb, const bf16* __restrict__ hfp,
         const bf16* __restrict__ Bt, const float* __restrict__ bias,
         bf16* __restrict__ zbuf, bf16* __restrict__ rh,
         const int* __restrict__ slice_ptr, int use_slice,
         float* __restrict__ accp) {
  __shared__ __attribute__((aligned(16))) char smem[131072];
  bf16* As = (bf16*)smem;                 // [2][256*64]
  bf16* Bs = (bf16*)(smem + 65536);       // [2][256*64]
  const int m0 = blockIdx.y * 256;
  const int n0 = blockIdx.x * 256;
  floatx4 acc[8][4];
#pragma unroll
  for (int i = 0; i < 8; ++i)
#pragma unroll
    for (int j = 0; j < 4; ++j) acc[i][j] = (floatx4)0.0f;

  mainloop8<256>(xb, hfp, Bt, As, Bs, m0, n0, acc);

  const int t = threadIdx.x;
  const int lane = t & 63, w = t >> 6;
  const int wm = w & 1, wn = w >> 1;
  const int q = lane >> 4, r16 = lane & 15;
  float* lds_f = (float*)smem;            // [128][256] f32 per half-pass
  const bool zmode = (n0 < GG);           // block-uniform (BN divides GG)
  const int nmin = use_slice ? *slice_ptr : 0;
  float bn[4];
#pragma unroll
  for (int j = 0; j < 4; ++j) bn[j] = bias[n0 + wn*64 + j*16 + r16];
  float lsum = 0.0f;

#pragma unroll
  for (int p = 0; p < 2; ++p) {           // two 128-row half-tiles (f32 = 128KB)
#pragma unroll
    for (int i4 = 0; i4 < 4; ++i4)
#pragma unroll
      for (int j = 0; j < 4; ++j) {
        const int n_loc = wn*64 + j*16 + r16;
        const int n = n0 + n_loc;
#pragma unroll
        for (int rr = 0; rr < 4; ++rr) {
          const int lr = wm*64 + i4*16 + q*4 + rr;
          float v = acc[p*4 + i4][j][rr] + bn[j];
          float s = 1.0f / (1.0f + __expf(-v));
          float ov;
          if (zmode) {
            float z = 0.875f * s + 0.125f;
            if (n >= nmin) lsum += -__log2f(z);
            ov = z;
          } else {
            ov = s;
          }
          lds_f[lr*256 + ((((n_loc >> 2) ^ (lr & 7)) << 2) | (n_loc & 3))] = ov;
        }
      }
    __syncthreads();
#pragma unroll
    for (int s2 = 0; s2 < 16; ++s2) {     // wave reads full rows -> 512B stores
      const int r = w*16 + s2;
      const int c = lane;
      floatx4 v4 = *(const floatx4*)&lds_f[r*256 + ((c ^ (r & 7)) << 2)];
      const int m = m0 + (r >> 6)*128 + p*64 + (r & 63);
      const int ncol = n0 + c*4;
      if (zmode) {
        bf16 o[4];
#pragma unroll
        for (int e = 0; e < 4; ++e) o[e] = __float2bfloat16(v4[e]);
        *(short4e*)&zbuf[(size_t)m * GG + ncol] = *(short4e*)o;
      } else {
        const int jc = ncol - GG;
        short4e hv = *(const short4e*)&hfp[(size_t)m * GG + jc];
        bf16 o[4];
#pragma unroll
        for (int e = 0; e < 4; ++e) {
          float hfv = __uint_as_float((unsigned)(unsigned short)hv[e] << 16);
          o[e] = __float2bfloat16(v4[e] * hfv);
        }
        *(short4e*)&rh[(size_t)m * GG + jc] = *(short4e*)o;
      }
    }
    __syncthreads();
  }
#pragma unroll
  for (int off = 32; off > 0; off >>= 1) lsum += __shfl_down(lsum, off, 64);
  float* sf = (float*)smem;
  if (lane == 0) sf[w] = lsum;
  __syncthreads();
  if (t == 0)
    atomicAdd(accp, sf[0]+sf[1]+sf[2]+sf[3]+sf[4]+sf[5]+sf[6]+sf[7]);
}

// ---------------- g stage (256x128): tanh + fixed-point update + outputs ----
__global__ void __launch_bounds__(512, 2)
gemm_g8(const bf16* __restrict__ xb, const bf16* __restrict__ rh,
        const bf16* __restrict__ Bt, const float* __restrict__ bias,
        const bf16* __restrict__ zbuf, const int* __restrict__ hidden,
        int col_off,
        float* __restrict__ out0, float* __restrict__ out1,
        bf16* __restrict__ hf_out, int write_hf,
        int write_bits, const float* __restrict__ accp,
        const int* __restrict__ slice_ptr, float* __restrict__ out2) {
  __shared__ __attribute__((aligned(16))) char smem[131072];
  bf16* As = (bf16*)smem;                 // [2][256*64]
  bf16* Bs = (bf16*)(smem + 65536);       // [2][128*64]
  const int m0 = blockIdx.y * 256;
  const int n0 = blockIdx.x * 128;
  floatx4 acc[8][2];
#pragma unroll
  for (int i = 0; i < 8; ++i)
#pragma unroll
    for (int j = 0; j < 2; ++j) acc[i][j] = (floatx4)0.0f;

  mainloop8<128>(xb, rh, Bt, As, Bs, m0, n0, acc);

  const int t = threadIdx.x;
  const int lane = t & 63, w = t >> 6;
  const int wm = w & 1, wn = w >> 1;
  const int q = lane >> 4, r16 = lane & 15;
  float* lds_f = (float*)smem;            // [256][128] f32 = 128KB, single pass
  float bn[2];
#pragma unroll
  for (int j = 0; j < 2; ++j) bn[j] = bias[n0 + wn*32 + j*16 + r16];

#pragma unroll
  for (int i = 0; i < 8; ++i)
#pragma unroll
    for (int j = 0; j < 2; ++j) {
      const int n_loc = wn*32 + j*16 + r16;
#pragma unroll
      for (int rr = 0; rr < 4; ++rr) {
        const int lr = wm*128 + i*16 + q*4 + rr;
        lds_f[lr*128 + ((((n_loc >> 2) ^ (lr & 7)) << 2) | (n_loc & 3))] =
            acc[i][j][rr] + bn[j];
      }
    }
  __syncthreads();
#pragma unroll
  for (int s2 = 0; s2 < 16; ++s2) {       // half-wave reads full rows
    const int r = w*2 + (lane >> 5) + s2*16;
    const int c = lane & 31;
    floatx4 v4 = *(const floatx4*)&lds_f[r*128 + ((c ^ (r & 7)) << 2)];
    const int m = m0 + r;
    const int ncol = n0 + c*4;
    short4e zb = *(const short4e*)&zbuf[(size_t)m * GG + ncol];
    int4 hd = *(const int4*)&hidden[(size_t)m * HSZ + col_off + ncol];
    const int hvv[4] = {hd.x, hd.y, hd.z, hd.w};
    floatx4 w0, w1;
    bf16 ob[4];
#pragma unroll
    for (int e = 0; e < 4; ++e) {
      float v = v4[e];
      float ex = __expf(2.0f * v);
      float gg = 1.0f - 2.0f / (ex + 1.0f);          // tanh(v)
      float z = __uint_as_float((unsigned)(unsigned short)zb[e] << 16);
      int zfix = (int)(z * 1024.0f);                 // trunc (z > 0)
      if (zfix < 1) zfix = 1;
      long long h = hvv[e];
      long long hupd = (h * (long long)zfix) >> 10;  // floor div 2^10
      float t2f = (1.0f - z) * gg * 8388608.0f;      // *2^23
      long long f2 = (long long)t2f;                 // trunc toward zero
      int hnew = (int)(hupd + f2);
      w0[e] = (float)hnew;
      w1[e] = (float)hnew * (1.0f / 8388608.0f);
      ob[e] = __float2bfloat16(w1[e]);
    }
    const size_t ob_ = (size_t)m * HSZ + col_off + ncol;
    *(floatx4*)&out0[ob_] = w0;
    *(floatx4*)&out1[ob_] = w1;
    if (write_hf) *(short4e*)&hf_out[(size_t)m * GG + ncol] = *(short4e*)ob;
  }
  if (write_bits && blockIdx.x == 0 && blockIdx.y == 0 && t == 0)
    *out2 = *accp + 32.0f * (float)(*slice_ptr) * (float)BATCH;
}

extern "C" void kernel_launch(void* const* d_in, const int* in_sizes, int n_in,
                              void* d_out, int out_size, void* d_ws, size_t ws_size,
                              hipStream_t stream) {
  const float* x      = (const float*)d_in[0];
  const int*   hidden = (const int*)d_in[1];
  const float* W_zr1  = (const float*)d_in[2];
  const float* b_zr1  = (const float*)d_in[3];
  const float* W_g1   = (const float*)d_in[4];
  const float* b_g1   = (const float*)d_in[5];
  const float* W_zr2  = (const float*)d_in[6];
  const float* b_zr2  = (const float*)d_in[7];
  const float* W_g2   = (const float*)d_in[8];
  const float* b_g2   = (const float*)d_in[9];
  const int*   slice  = (const int*)d_in[10];

  char* ws = (char*)d_ws;
  size_t off = 0;
  auto alloc = [&](size_t bytes) -> void* {
    void* p = ws + off;
    off += (bytes + 255) & ~(size_t)255;
    return p;
  };
  bf16* xb     = (bf16*)alloc((size_t)BATCH * IN_SZ * 2);
  bf16* wt_zr1 = (bf16*)alloc((size_t)2048 * 2048 * 2);
  bf16* wt_g1  = (bf16*)alloc((size_t)1024 * 2048 * 2);
  bf16* wt_zr2 = (bf16*)alloc((size_t)2048 * 2048 * 2);
  bf16* wt_g2  = (bf16*)alloc((size_t)1024 * 2048 * 2);
  bf16* hf     = (bf16*)alloc((size_t)BATCH * GG * 2);
  bf16* rh     = (bf16*)alloc((size_t)BATCH * GG * 2);
  bf16* zbuf   = (bf16*)alloc((size_t)BATCH * GG * 2);
  float* accp  = (float*)alloc(256);

  float* out0 = (float*)d_out;
  float* out1 = out0 + (size_t)BATCH * HSZ;
  float* out2 = out0 + 2 * (size_t)BATCH * HSZ;

  prep_all<<<3072 + 8192, 256, 0, stream>>>(x, xb, hidden, hf, accp,
                                            W_zr1, W_g1, W_zr2, W_g2,
                                            wt_zr1, wt_g1, wt_zr2, wt_g2);

  // stage 1: zr1 = sigmoid([x|h2f] @ W_zr1 + b)
  gemm_zr8<<<dim3(8, 32), 512, 0, stream>>>(xb, hf, wt_zr1, b_zr1, zbuf, rh, slice, 1, accp);
  // stage 2: g1 = tanh([x|r1*h2f] @ W_g1 + b); h1 update; writes h1_fl into hf
  gemm_g8<<<dim3(8, 32), 512, 0, stream>>>(xb, rh, wt_g1, b_g1, zbuf, hidden, 0,
                                           out0, out1, hf, 1, 0, accp, slice, out2);
  // stage 3: zr2 = sigmoid([x|h1f] @ W_zr2 + b)
  gemm_zr8<<<dim3(8, 32), 512, 0, stream>>>(xb, hf, wt_zr2, b_zr2, zbuf, rh, slice, 0, accp);
  // stage 4: g2 = tanh([x|r2*h1f] @ W_g2 + b); h2 update; writes optimal_bits
  gemm_g8<<<dim3(8, 32), 512, 0, stream>>>(xb, rh, wt_g2, b_g2, zbuf, hidden, 1024,
                                           out0, out1, hf, 0, 1, accp, slice, out2);
}